// Round 1
// baseline (11.993 us; speedup 1.0000x reference)
//
#include <hip/hip_runtime.h>

// out[b, h2*256 + w2] = cos(x[b,0,2h2,2w2]/255) * cos(x[b,0,2h2+1,2w2]/255) * cos(x[b,0,2h2+1,2w2+1]/255)
//
// Derivation: <ZZZZ> after the CX chain = sum_s prob[s]*eff[s]; the composed CX
// permutation T is GF(2)-linear, eff[t] = (-1)^<w,t> with w=(T^T)^{-1}*(1,1,1,1)
// = (1,0,1,1) over qubits (0,1,2,3). Product state => expectation factorizes:
// qubits 0,2,3 give cos(theta_i), qubit 1 gives 1. theta_i = patch[i]/255.

constexpr int H = 512, W = 512;
constexpr int H2 = H / 2, W2 = W / 2;     // 256 x 256 patches
constexpr int PPB = H2 * W2;              // 65536 patches per batch image
constexpr float INV255 = 1.0f / 255.0f;

__global__ __launch_bounds__(256) void qpe_kernel(const float* __restrict__ x,
                                                  float* __restrict__ out) {
    int g = blockIdx.x * blockDim.x + threadIdx.x;  // one thread = 4 patches
    int b   = g >> 14;        // / 16384 quads per batch
    int rem = g & 16383;
    int h2  = rem >> 6;       // patch row
    int wq  = rem & 63;       // quad index within row (64 quads * 4 patches = 256)

    const float* xb = x + (size_t)b * (H * W);
    int r0 = 2 * h2;
    int c0 = 8 * wq;          // byte offset 32B-aligned -> clean float4 loads

    const float4* p0 = (const float4*)(xb + (size_t)r0 * W + c0);        // even row
    const float4* p1 = (const float4*)(xb + (size_t)(r0 + 1) * W + c0);  // odd row
    float4 a0 = p0[0];
    float4 a1 = p0[1];
    float4 b0 = p1[0];
    float4 b1 = p1[1];

    float4 o;
    o.x = __cosf(a0.x * INV255) * __cosf(b0.x * INV255) * __cosf(b0.y * INV255);
    o.y = __cosf(a0.z * INV255) * __cosf(b0.z * INV255) * __cosf(b0.w * INV255);
    o.z = __cosf(a1.x * INV255) * __cosf(b1.x * INV255) * __cosf(b1.y * INV255);
    o.w = __cosf(a1.z * INV255) * __cosf(b1.z * INV255) * __cosf(b1.w * INV255);

    float4* po = (float4*)(out + (size_t)b * PPB + (size_t)h2 * W2 + wq * 4);
    *po = o;
}

extern "C" void kernel_launch(void* const* d_in, const int* in_sizes, int n_in,
                              void* d_out, int out_size, void* d_ws, size_t ws_size,
                              hipStream_t stream) {
    const float* x = (const float*)d_in[0];
    float* out = (float*)d_out;
    // 32 batches * 65536 patches / 4 patches-per-thread = 524288 threads
    const int threads = 256;
    const int blocks = (32 * PPB / 4) / threads;  // 2048
    qpe_kernel<<<blocks, threads, 0, stream>>>(x, out);
}

// Round 2
// 11.477 us; speedup vs baseline: 1.0450x; 1.0450x over previous
//
#include <hip/hip_runtime.h>

// out[b, h2*256 + w2] = cos(x[b,0,2h2,2w2]/255) * cos(x[b,0,2h2+1,2w2]/255) * cos(x[b,0,2h2+1,2w2+1]/255)
//
// Derivation: <ZZZZ> after the CX chain = sum_s prob[s]*eff[s]; the composed CX
// permutation T is GF(2)-linear, eff[t] = (-1)^<w,t> with w=(T^T)^{-1}*(1,1,1,1)
// = (1,0,1,1) over qubits (0,1,2,3). Product state => expectation factorizes:
// qubits 0,2,3 give cos(theta_i), qubit 1 gives 1. theta_i = patch[i]/255.
//
// Layout: 2 horizontally-adjacent patches per thread -> every global load
// instruction is lane-dense (lane i reads base+16i, 1KB/wave-instr), store is
// dense 8B/lane. v_cos_f32 takes revolutions; fold 1/255 and 1/(2pi) into one
// multiply: cos(x/255) = cos_rev(x * (1/(255*2pi))).

constexpr int H = 512, W = 512;
constexpr int H2 = H / 2, W2 = W / 2;     // 256 x 256 patches
constexpr int PPB = H2 * W2;              // 65536 patches per batch image
constexpr float KREV = 1.0f / (255.0f * 6.28318530717958647692f); // 1/(255*2pi)

#if defined(__has_builtin)
#if __has_builtin(__builtin_amdgcn_cosf)
#define COS_REV(x) __builtin_amdgcn_cosf(x)
#else
#define COS_REV(x) __cosf((x) * 6.28318530717958647692f)
#endif
#else
#define COS_REV(x) __cosf((x) * 6.28318530717958647692f)
#endif

__global__ __launch_bounds__(256) void qpe_kernel(const float* __restrict__ x,
                                                  float* __restrict__ out) {
    int g = blockIdx.x * blockDim.x + threadIdx.x;  // one thread = 2 patches
    int b   = g >> 15;        // 32768 pairs per batch image
    int rem = g & 32767;
    int h2  = rem >> 7;       // patch row (128 pairs per row)
    int wp  = rem & 127;      // pair index within row

    const float* xb = x + (size_t)b * (H * W);
    int r0 = 2 * h2;
    int c0 = 4 * wp;          // 16B-aligned

    float4 ev = *(const float4*)(xb + (size_t)r0 * W + c0);        // even row
    float4 od = *(const float4*)(xb + (size_t)(r0 + 1) * W + c0);  // odd row

    float2 o;
    o.x = COS_REV(ev.x * KREV) * COS_REV(od.x * KREV) * COS_REV(od.y * KREV);
    o.y = COS_REV(ev.z * KREV) * COS_REV(od.z * KREV) * COS_REV(od.w * KREV);

    *(float2*)(out + (size_t)b * PPB + (size_t)h2 * W2 + 2 * wp) = o;
}

extern "C" void kernel_launch(void* const* d_in, const int* in_sizes, int n_in,
                              void* d_out, int out_size, void* d_ws, size_t ws_size,
                              hipStream_t stream) {
    const float* x = (const float*)d_in[0];
    float* out = (float*)d_out;
    // 32 batches * 65536 patches / 2 patches-per-thread = 1048576 threads
    const int threads = 256;
    const int blocks = (32 * PPB / 2) / threads;  // 4096
    qpe_kernel<<<blocks, threads, 0, stream>>>(x, out);
}

// Round 4
// 10.682 us; speedup vs baseline: 1.1227x; 1.0743x over previous
//
#include <hip/hip_runtime.h>

// out[b, h2*256 + w2] = cos(x[b,0,2h2,2w2]/255) * cos(x[b,0,2h2+1,2w2]/255) * cos(x[b,0,2h2+1,2w2+1]/255)
//
// Derivation: <ZZZZ> after the CX chain = sum_s prob[s]*eff[s]; the composed CX
// permutation T is GF(2)-linear, eff[t] = (-1)^<w,t> with w=(T^T)^{-1}*(1,1,1,1)
// = (1,0,1,1) over qubits (0,1,2,3). Product state => expectation factorizes:
// qubits 0,2,3 give cos(theta_i), qubit 1 gives 1. theta_i = patch[i]/255.
//
// Layout: 2 horizontally-adjacent patches per thread -> every global load
// instruction is lane-dense (lane i reads base+16i, 1KB/wave-instr), store is
// dense 8B/lane nontemporal (output never re-read; keep input lines resident
// in L2/L3 across graph replays instead of write-allocating output lines).
// Note: __builtin_nontemporal_store needs a clang native vector, not HIP float2.

constexpr int H = 512, W = 512;
constexpr int H2 = H / 2, W2 = W / 2;     // 256 x 256 patches
constexpr int PPB = H2 * W2;              // 65536 patches per batch image
constexpr float KREV = 1.0f / (255.0f * 6.28318530717958647692f); // 1/(255*2pi)

typedef float f32x2 __attribute__((ext_vector_type(2)));

#if defined(__has_builtin)
#if __has_builtin(__builtin_amdgcn_cosf)
#define COS_REV(x) __builtin_amdgcn_cosf(x)
#else
#define COS_REV(x) __cosf((x) * 6.28318530717958647692f)
#endif
#else
#define COS_REV(x) __cosf((x) * 6.28318530717958647692f)
#endif

__global__ __launch_bounds__(256) void qpe_kernel(const float* __restrict__ x,
                                                  float* __restrict__ out) {
    int g = blockIdx.x * blockDim.x + threadIdx.x;  // one thread = 2 patches
    int b   = g >> 15;        // 32768 pairs per batch image
    int rem = g & 32767;
    int h2  = rem >> 7;       // patch row (128 pairs per row)
    int wp  = rem & 127;      // pair index within row

    const float* xb = x + (size_t)b * (H * W);
    int r0 = 2 * h2;
    int c0 = 4 * wp;          // 16B-aligned

    float4 ev = *(const float4*)(xb + (size_t)r0 * W + c0);        // even row
    float4 od = *(const float4*)(xb + (size_t)(r0 + 1) * W + c0);  // odd row

    f32x2 o;
    o.x = COS_REV(ev.x * KREV) * COS_REV(od.x * KREV) * COS_REV(od.y * KREV);
    o.y = COS_REV(ev.z * KREV) * COS_REV(od.z * KREV) * COS_REV(od.w * KREV);

    f32x2* po = (f32x2*)(out + (size_t)b * PPB + (size_t)h2 * W2 + 2 * wp);
    __builtin_nontemporal_store(o, po);
}

extern "C" void kernel_launch(void* const* d_in, const int* in_sizes, int n_in,
                              void* d_out, int out_size, void* d_ws, size_t ws_size,
                              hipStream_t stream) {
    const float* x = (const float*)d_in[0];
    float* out = (float*)d_out;
    // 32 batches * 65536 patches / 2 patches-per-thread = 1048576 threads
    const int threads = 256;
    const int blocks = (32 * PPB / 2) / threads;  // 4096
    qpe_kernel<<<blocks, threads, 0, stream>>>(x, out);
}